// Round 10
// baseline (269.259 us; speedup 1.0000x reference)
//
#include <hip/hip_runtime.h>
#include <hip/hip_fp16.h>

#define T_TOK 1024
#define H_DIM 2048
#define I_DIM 1408
#define N_EXP 8
#define TOPK  2

using f16x8 = __attribute__((ext_vector_type(8))) _Float16;
using f32x4 = __attribute__((ext_vector_type(4))) float;

#define BM 64
#define BN 64
#define BK 64
#define NTHR 256

// Barrier without vmcnt drain: only ds_writes must land (lgkmcnt), global
// loads legally stay in flight (r9-verified safe, same numerics).
#define BAR()                                                     \
    do {                                                          \
        asm volatile("s_waitcnt lgkmcnt(0)" ::: "memory");        \
        __builtin_amdgcn_s_barrier();                             \
    } while (0)

// ---------------- workspace layout (bytes) ----------------
#define WS_COUNTS      0                         // int[8]
#define WS_CURSORS     512                       // int[8]   (same memset range)
#define WS_TOPK_E      768                       // int[2048]
#define WS_TOPK_W      (768 + 8192)              // float[2048]
#define WS_TOK_OF_SLOT 17408                     // int[3072] (padded slots <= 2552)
#define WS_W_OF_SLOT   29696                     // float[3072]
#define WS_HACT        43008                     // f16[3072*1408] = 8650752 B
#define WS_NEEDED      (43008 + 8650752)

// 8-expert padded prefix, computed inline wherever needed (kills k_prefix)
__device__ __forceinline__ void prefix_of(const int* counts, int e, int& base, int& cnt) {
    int b = 0;
#pragma unroll
    for (int q = 0; q < N_EXP; ++q) {
        int c = counts[q];
        if (q == e) { base = b; cnt = c; }
        b += ((c + BM - 1) / BM) * BM;
    }
}

// ---------------- router (also zeroes `out` for gemm2 atomics) ----------------
__global__ void k_router(const float* __restrict__ X, const float* __restrict__ GW,
                         int* __restrict__ counts, int* __restrict__ topk_e,
                         float* __restrict__ topk_w, float* __restrict__ out) {
    int gtid = blockIdx.x * blockDim.x + threadIdx.x;
    // zero out[] (2M floats) across the 65536 threads of this grid
    float4* o4 = (float4*)out;
    for (int i = gtid; i < T_TOK * H_DIM / 4; i += (T_TOK / 4) * 256)
        o4[i] = float4{0.f, 0.f, 0.f, 0.f};

    int t = gtid >> 6;
    int lane = threadIdx.x & 63;
    if (t >= T_TOK) return;
    float acc[N_EXP];
#pragma unroll
    for (int e = 0; e < N_EXP; ++e) acc[e] = 0.f;
    const float* xrow = X + (size_t)t * H_DIM;
    for (int h = lane; h < H_DIM; h += 64) {
        float x = xrow[h];
        const float* g = GW + (size_t)h * N_EXP;
#pragma unroll
        for (int e = 0; e < N_EXP; ++e) acc[e] = fmaf(x, g[e], acc[e]);
    }
#pragma unroll
    for (int off = 32; off > 0; off >>= 1) {
#pragma unroll
        for (int e = 0; e < N_EXP; ++e) acc[e] += __shfl_xor(acc[e], off, 64);
    }
    if (lane == 0) {
        float m = acc[0];
#pragma unroll
        for (int e = 1; e < N_EXP; ++e) m = fmaxf(m, acc[e]);
        float ex[N_EXP], s = 0.f;
#pragma unroll
        for (int e = 0; e < N_EXP; ++e) { ex[e] = expf(acc[e] - m); s += ex[e]; }
        float inv = 1.f / s;
        int e1 = 0;
#pragma unroll
        for (int e = 1; e < N_EXP; ++e) if (ex[e] > ex[e1]) e1 = e;
        int e2 = (e1 == 0) ? 1 : 0;
#pragma unroll
        for (int e = 0; e < N_EXP; ++e) if (e != e1 && ex[e] > ex[e2]) e2 = e;
        topk_e[t * 2 + 0] = e1;
        topk_e[t * 2 + 1] = e2;
        topk_w[t * 2 + 0] = ex[e1] * inv;
        topk_w[t * 2 + 1] = ex[e2] * inv;
        atomicAdd(&counts[e1], 1);
        atomicAdd(&counts[e2], 1);
    }
}

__global__ void k_scatter(const int* __restrict__ topk_e, const float* __restrict__ topk_w,
                          const int* __restrict__ counts, int* __restrict__ cursors,
                          int* __restrict__ tok_of_slot, float* __restrict__ w_of_slot) {
    int t = blockIdx.x * blockDim.x + threadIdx.x;
    if (t >= T_TOK) return;
    for (int j = 0; j < TOPK; ++j) {
        int e = topk_e[t * 2 + j];
        int base, cnt;
        prefix_of(counts, e, base, cnt);
        int pos = atomicAdd(&cursors[e], 1);
        int slot = base + pos;
        tok_of_slot[slot] = t;
        w_of_slot[slot] = topk_w[t * 2 + j];
    }
}

// ===== GEMM common: 64x64 tile, BK=64, 256 thr (4 waves, 2x2 of 32x32).
// B staged in LDS (XOR-swizzled, r5-verified-balanced maps, 0 conflicts),
// A read DIRECT from global into fragments (wave-private rows; L1/L2-hot),
// drain-free barriers, 2-deep B register prefetch. =====

#define MFMA4()                                                                 \
    _Pragma("unroll") for (int ii = 0; ii < 2; ++ii)                            \
        _Pragma("unroll") for (int jj = 0; jj < 2; ++jj)                        \
            acc[ii][jj] = __builtin_amdgcn_mfma_f32_16x16x32_f16(af[ii], bf[jj], acc[ii][jj], 0, 0, 0);

#define BF_READ(buf, ks)                                                        \
    _Pragma("unroll") for (int jj = 0; jj < 2; ++jj) {                          \
        int col = wn + jj * 16 + rsel;                                          \
        bf[jj] = *(const f16x8*)&Bs[buf][col][((kq + 4 * (ks)) ^ (col & 7)) * 8]; \
    }

// B staging: thread -> (1 col, 16 k-rows = 2 slot-groups). r5-verified balanced.
#define LOADB(bS, k0)                                                           \
    do {                                                                        \
        const float* bp = bcol + (size_t)(k0) * LDB;                            \
        _Pragma("unroll") for (int j = 0; j < 16; ++j)                          \
            bS[j] = bp[(size_t)j * LDB];                                        \
    } while (0)

#define STOREB(buf, bS)                                                         \
    do {                                                                        \
        f16x8 q0, q1;                                                           \
        _Pragma("unroll") for (int j = 0; j < 8; ++j) {                         \
            q0[j] = (_Float16)bS[j]; q1[j] = (_Float16)bS[j + 8];               \
        }                                                                       \
        *(f16x8*)&Bs[buf][bn][((bc2) ^ (bn & 7)) * 8] = q0;                     \
        *(f16x8*)&Bs[buf][bn][((bc2 + 1) ^ (bn & 7)) * 8] = q1;                 \
    } while (0)

// ---------------- GEMM1: hact[slot, i] = silu(x[tok] . w1[e,:,i]) * w_slot ----------------
__global__ __launch_bounds__(NTHR, 4) void k_gemm1(
    const float* __restrict__ X, const float* __restrict__ W1,
    const int* __restrict__ counts, const int* __restrict__ tok_of_slot,
    const float* __restrict__ w_of_slot, _Float16* __restrict__ hact) {
    __shared__ _Float16 Bs[2][BN][BK];

    const int e = blockIdx.z;
    int base, cnt;
    prefix_of(counts, e, base, cnt);
    const int m0 = blockIdx.y * BM;
    if (m0 >= cnt) return;
    const int n0 = blockIdx.x * BN;
    const int tid = threadIdx.x;
    const int LDB = I_DIM;

    const int bn = tid & 63;
    const int bc2 = (tid >> 6) * 2;
    const float* bcol = W1 + (size_t)e * (H_DIM * I_DIM) + (size_t)(bc2 * 8) * I_DIM + n0 + bn;

    const int wid = tid >> 6, lane = tid & 63;
    const int wm = (wid >> 1) * 32, wn = (wid & 1) * 32;
    const int rsel = lane & 15, kq = lane >> 4;

    // A direct-row pointers (one per 16-row fragment), clamped
    const float* arowp[2];
#pragma unroll
    for (int ii = 0; ii < 2; ++ii) {
        int r = wm + ii * 16 + rsel;
        int rr = min(r, cnt - m0 - 1);
        arowp[ii] = X + (size_t)tok_of_slot[base + m0 + rr] * H_DIM + kq * 8;
    }

    f32x4 acc[2][2] = {};
    float bS0[16], bS1[16];

#define COMPUTE1(buf, kbase)                                                    \
    do {                                                                        \
        _Pragma("unroll") for (int ks = 0; ks < 2; ++ks) {                      \
            f16x8 af[2], bf[2];                                                 \
            _Pragma("unroll") for (int ii = 0; ii < 2; ++ii) {                  \
                float a8[8];                                                    \
                const float* ap = arowp[ii] + (kbase) + ks * 32;                \
                *(float4*)(a8 + 0) = *(const float4*)(ap);                      \
                *(float4*)(a8 + 4) = *(const float4*)(ap + 4);                  \
                _Pragma("unroll") for (int c = 0; c < 8; ++c)                   \
                    af[ii][c] = (_Float16)a8[c];                                \
            }                                                                   \
            BF_READ(buf, ks);                                                   \
            MFMA4();                                                            \
        }                                                                       \
    } while (0)

    constexpr int KT = H_DIM / BK;   // 32, even
    LOADB(bS0, 0);
    STOREB(0, bS0);
    LOADB(bS0, BK);
    BAR();
    for (int kt = 0; kt < KT; kt += 2) {
        if (kt + 2 < KT) LOADB(bS1, (kt + 2) * BK);
        COMPUTE1(0, kt * BK);
        if (kt + 1 < KT) STOREB(1, bS0);
        BAR();
        if (kt + 3 < KT) LOADB(bS0, (kt + 3) * BK);
        if (kt + 1 < KT) {
            COMPUTE1(1, (kt + 1) * BK);
            if (kt + 2 < KT) STOREB(0, bS1);
            BAR();
        }
    }
#undef COMPUTE1

    const int rows = cnt - m0;
#pragma unroll
    for (int i = 0; i < 2; ++i) {
#pragma unroll
        for (int rg = 0; rg < 4; ++rg) {
            int r = wm + i * 16 + kq * 4 + rg;
            if (r < rows) {
                int slot = base + m0 + r;
                float w = w_of_slot[slot];
                _Float16* hrow = hact + (size_t)slot * I_DIM + n0;
#pragma unroll
                for (int j = 0; j < 2; ++j) {
                    float v = acc[i][j][rg];
                    hrow[wn + j * 16 + rsel] = (_Float16)(v / (1.f + expf(-v)) * w);
                }
            }
        }
    }
}

// ---------------- GEMM2: out[tok, h] += hact[slot, :] . w2[e, :, h] ----------------
__global__ __launch_bounds__(NTHR, 4) void k_gemm2(
    const _Float16* __restrict__ hact, const float* __restrict__ W2,
    const int* __restrict__ counts, const int* __restrict__ tok_of_slot,
    float* __restrict__ out) {
    __shared__ _Float16 Bs[2][BN][BK];

    const int e = blockIdx.z;
    int base, cnt;
    prefix_of(counts, e, base, cnt);
    const int m0 = blockIdx.y * BM;
    if (m0 >= cnt) return;
    const int n0 = blockIdx.x * BN;
    const int tid = threadIdx.x;
    const int LDB = H_DIM;

    const int bn = tid & 63;
    const int bc2 = (tid >> 6) * 2;
    const float* bcol = W2 + (size_t)e * (I_DIM * H_DIM) + (size_t)(bc2 * 8) * H_DIM + n0 + bn;

    const int wid = tid >> 6, lane = tid & 63;
    const int wm = (wid >> 1) * 32, wn = (wid & 1) * 32;
    const int rsel = lane & 15, kq = lane >> 4;

    const _Float16* arowp[2];
#pragma unroll
    for (int ii = 0; ii < 2; ++ii) {
        int r = wm + ii * 16 + rsel;
        int rr = min(r, cnt - m0 - 1);
        arowp[ii] = hact + (size_t)(base + m0 + rr) * I_DIM + kq * 8;
    }

    f32x4 acc[2][2] = {};
    float bS0[16], bS1[16];

#define COMPUTE2(buf, kbase)                                                    \
    do {                                                                        \
        _Pragma("unroll") for (int ks = 0; ks < 2; ++ks) {                      \
            f16x8 af[2], bf[2];                                                 \
            _Pragma("unroll") for (int ii = 0; ii < 2; ++ii)                    \
                af[ii] = *(const f16x8*)(arowp[ii] + (kbase) + ks * 32);        \
            BF_READ(buf, ks);                                                   \
            MFMA4();                                                            \
        }                                                                       \
    } while (0)

    constexpr int KT = I_DIM / BK;   // 22, even
    LOADB(bS0, 0);
    STOREB(0, bS0);
    LOADB(bS0, BK);
    BAR();
    for (int kt = 0; kt < KT; kt += 2) {
        if (kt + 2 < KT) LOADB(bS1, (kt + 2) * BK);
        COMPUTE2(0, kt * BK);
        if (kt + 1 < KT) STOREB(1, bS0);
        BAR();
        if (kt + 3 < KT) LOADB(bS0, (kt + 3) * BK);
        if (kt + 1 < KT) {
            COMPUTE2(1, (kt + 1) * BK);
            if (kt + 2 < KT) STOREB(0, bS1);
            BAR();
        }
    }
#undef COMPUTE2

    const int rows = cnt - m0;
#pragma unroll
    for (int i = 0; i < 2; ++i) {
#pragma unroll
        for (int rg = 0; rg < 4; ++rg) {
            int r = wm + i * 16 + kq * 4 + rg;
            if (r < rows) {
                int slot = base + m0 + r;
                int tok = tok_of_slot[slot];
                float* orow = out + (size_t)tok * H_DIM + n0;
#pragma unroll
                for (int j = 0; j < 2; ++j)
                    atomicAdd(&orow[wn + j * 16 + rsel], acc[i][j][rg]);
            }
        }
    }
}

extern "C" void kernel_launch(void* const* d_in, const int* in_sizes, int n_in,
                              void* d_out, int out_size, void* d_ws, size_t ws_size,
                              hipStream_t stream) {
    const float* X  = (const float*)d_in[0];
    const float* GW = (const float*)d_in[1];
    const float* W1 = (const float*)d_in[2];
    const float* W2 = (const float*)d_in[3];
    float* out = (float*)d_out;
    char* ws = (char*)d_ws;
    if (ws_size < (size_t)WS_NEEDED) return;

    int*   counts      = (int*)(ws + WS_COUNTS);
    int*   cursors     = (int*)(ws + WS_CURSORS);
    int*   topk_e      = (int*)(ws + WS_TOPK_E);
    float* topk_w      = (float*)(ws + WS_TOPK_W);
    int*   tok_of_slot = (int*)(ws + WS_TOK_OF_SLOT);
    float* w_of_slot   = (float*)(ws + WS_W_OF_SLOT);
    _Float16* hact     = (_Float16*)(ws + WS_HACT);

    hipMemsetAsync(ws, 0, 768, stream);                       // counts + cursors
    k_router<<<T_TOK / 4, 256, 0, stream>>>(X, GW, counts, topk_e, topk_w, out);
    k_scatter<<<T_TOK / 256, 256, 0, stream>>>(topk_e, topk_w, counts, cursors,
                                               tok_of_slot, w_of_slot);
    // per-expert cnt <= 1024 -> up to 16 m-blocks of 64
    k_gemm1<<<dim3(I_DIM / BN, 16, N_EXP), NTHR, 0, stream>>>(
        X, W1, counts, tok_of_slot, w_of_slot, hact);
    k_gemm2<<<dim3(H_DIM / BN, 16, N_EXP), NTHR, 0, stream>>>(
        hact, W2, counts, tok_of_slot, out);
}

// Round 11
// 250.656 us; speedup vs baseline: 1.0742x; 1.0742x over previous
//
#include <hip/hip_runtime.h>
#include <hip/hip_fp16.h>

#define T_TOK 1024
#define H_DIM 2048
#define I_DIM 1408
#define N_EXP 8
#define TOPK  2

using f16x8 = __attribute__((ext_vector_type(8))) _Float16;
using f32x4 = __attribute__((ext_vector_type(4))) float;

#define BM 128
#define BN 64
#define BK 64
#define NTHR 512

// Barrier without vmcnt drain (r9-verified neutral/safe): ds_writes drained,
// global prefetch loads stay in flight.
#define BAR()                                                     \
    do {                                                          \
        asm volatile("s_waitcnt lgkmcnt(0)" ::: "memory");        \
        __builtin_amdgcn_s_barrier();                             \
    } while (0)

// ---------------- workspace layout (bytes) ----------------
#define WS_COUNTS      0                         // int[8]
#define WS_CURSORS     512                       // int[8]
#define WS_TOPK_E      768                       // int[2048]
#define WS_TOPK_W      (768 + 8192)              // float[2048]
#define WS_TOK_OF_SLOT 17408                     // int[3072]
#define WS_W_OF_SLOT   29696                     // float[3072]
#define WS_H32         43008                     // f32[3072*1408] = 17301504 B
#define WS_NEEDED      (43008 + 17301504)        // ~17.3 MB (< 22.5 MB known-safe)

// 8-expert padded prefix (pad to BM=128), inline
__device__ __forceinline__ void prefix_of(const int* counts, int e, int& base, int& cnt) {
    int b = 0;
#pragma unroll
    for (int q = 0; q < N_EXP; ++q) {
        int c = counts[q];
        if (q == e) { base = b; cnt = c; }
        b += ((c + BM - 1) / BM) * BM;
    }
}

// ---------------- router (also zeroes `out`) ----------------
__global__ void k_router(const float* __restrict__ X, const float* __restrict__ GW,
                         int* __restrict__ counts, int* __restrict__ topk_e,
                         float* __restrict__ topk_w, float* __restrict__ out) {
    int gtid = blockIdx.x * blockDim.x + threadIdx.x;
    float4* o4 = (float4*)out;
    for (int i = gtid; i < T_TOK * H_DIM / 4; i += (T_TOK / 4) * 256)
        o4[i] = float4{0.f, 0.f, 0.f, 0.f};

    int t = gtid >> 6;
    int lane = threadIdx.x & 63;
    if (t >= T_TOK) return;
    float acc[N_EXP];
#pragma unroll
    for (int e = 0; e < N_EXP; ++e) acc[e] = 0.f;
    const float* xrow = X + (size_t)t * H_DIM;
    for (int h = lane; h < H_DIM; h += 64) {
        float x = xrow[h];
        const float* g = GW + (size_t)h * N_EXP;
#pragma unroll
        for (int e = 0; e < N_EXP; ++e) acc[e] = fmaf(x, g[e], acc[e]);
    }
#pragma unroll
    for (int off = 32; off > 0; off >>= 1) {
#pragma unroll
        for (int e = 0; e < N_EXP; ++e) acc[e] += __shfl_xor(acc[e], off, 64);
    }
    if (lane == 0) {
        float m = acc[0];
#pragma unroll
        for (int e = 1; e < N_EXP; ++e) m = fmaxf(m, acc[e]);
        float ex[N_EXP], s = 0.f;
#pragma unroll
        for (int e = 0; e < N_EXP; ++e) { ex[e] = expf(acc[e] - m); s += ex[e]; }
        float inv = 1.f / s;
        int e1 = 0;
#pragma unroll
        for (int e = 1; e < N_EXP; ++e) if (ex[e] > ex[e1]) e1 = e;
        int e2 = (e1 == 0) ? 1 : 0;
#pragma unroll
        for (int e = 0; e < N_EXP; ++e) if (e != e1 && ex[e] > ex[e2]) e2 = e;
        topk_e[t * 2 + 0] = e1;
        topk_e[t * 2 + 1] = e2;
        topk_w[t * 2 + 0] = ex[e1] * inv;
        topk_w[t * 2 + 1] = ex[e2] * inv;
        atomicAdd(&counts[e1], 1);
        atomicAdd(&counts[e2], 1);
    }
}

__global__ void k_scatter(const int* __restrict__ topk_e, const float* __restrict__ topk_w,
                          const int* __restrict__ counts, int* __restrict__ cursors,
                          int* __restrict__ tok_of_slot, float* __restrict__ w_of_slot) {
    int t = blockIdx.x * blockDim.x + threadIdx.x;
    if (t >= T_TOK) return;
    for (int j = 0; j < TOPK; ++j) {
        int e = topk_e[t * 2 + j];
        int base, cnt;
        prefix_of(counts, e, base, cnt);
        int pos = atomicAdd(&cursors[e], 1);
        int slot = base + pos;
        tok_of_slot[slot] = t;
        w_of_slot[slot] = topk_w[t * 2 + j];
    }
}

// ===== GEMM inner structure: r3/r9-proven (0 conflicts, VGPR 60).
// 128x64 tile, BK=64, 512 thr (8 waves, 4x2 of 32x32), XOR-swizzled LDS,
// 2-deep register prefetch, drain-free barriers. =====

#define G_COMPUTE(buf)                                                          \
    do {                                                                        \
        _Pragma("unroll") for (int ks = 0; ks < 2; ++ks) {                      \
            f16x8 af[2], bf[2];                                                 \
            _Pragma("unroll") for (int ii = 0; ii < 2; ++ii) {                  \
                int r = wm + ii * 16 + rsel;                                    \
                af[ii] = *(const f16x8*)&As[buf][r][((kq + 4 * ks) ^ (r & 7)) * 8]; \
            }                                                                   \
            _Pragma("unroll") for (int jj = 0; jj < 2; ++jj) {                  \
                int r = wn + jj * 16 + rsel;                                    \
                bf[jj] = *(const f16x8*)&Bs[buf][r][((kq + 4 * ks) ^ (r & 7)) * 8]; \
            }                                                                   \
            _Pragma("unroll") for (int ii = 0; ii < 2; ++ii)                    \
                _Pragma("unroll") for (int jj = 0; jj < 2; ++jj)                \
                    acc[ii][jj] = __builtin_amdgcn_mfma_f32_16x16x32_f16(af[ii], bf[jj], acc[ii][jj], 0, 0, 0); \
        }                                                                       \
    } while (0)

// ---------------- GEMM1 (K-split x2): h32[slot,i] += x[tok] . w1[e, kh-half, i] ----------------
__global__ __launch_bounds__(NTHR, 4) void k_gemm1(
    const float* __restrict__ X, const float* __restrict__ W1,
    const int* __restrict__ counts, const int* __restrict__ tok_of_slot,
    float* __restrict__ h32) {
    __shared__ _Float16 As[2][BM][BK];
    __shared__ _Float16 Bs[2][BN][BK];

    const int e = blockIdx.z;
    int base, cnt;
    prefix_of(counts, e, base, cnt);
    const int mblk = blockIdx.y & 7;
    const int kh = blockIdx.y >> 3;             // 0,1 -> K halves of 1024
    const int m0 = mblk * BM;
    if (m0 >= cnt) return;
    const int n0 = blockIdx.x * BN;
    const int tid = threadIdx.x;

    const int ar = tid >> 2;
    const int ac2 = (tid & 3) * 2;
    const int r_eff = min(ar, cnt - m0 - 1);
    const float* arow = X + (size_t)tok_of_slot[base + m0 + r_eff] * H_DIM
                          + kh * 1024 + (tid & 3) * 16;

    const int bn = tid & 63;
    const int bc = tid >> 6;
    const float* bcol = W1 + (size_t)e * (H_DIM * I_DIM)
                           + (size_t)(kh * 1024 + bc * 8) * I_DIM + n0 + bn;

    const int wid = tid >> 6, lane = tid & 63;
    const int wm = (wid >> 1) * 32, wn = (wid & 1) * 32;
    const int rsel = lane & 15, kq = lane >> 4;

    f32x4 acc[2][2] = {};

    float4 aR0[4]; float bR0[8];
    float4 aR1[4]; float bR1[8];

#define LOAD1(aR, bR, k0)                                              \
    do {                                                               \
        aR[0] = *(const float4*)(arow + (k0));                         \
        aR[1] = *(const float4*)(arow + (k0) + 4);                     \
        aR[2] = *(const float4*)(arow + (k0) + 8);                     \
        aR[3] = *(const float4*)(arow + (k0) + 12);                    \
        const float* bp = bcol + (size_t)(k0) * I_DIM;                 \
        _Pragma("unroll") for (int j = 0; j < 8; ++j)                  \
            bR[j] = bp[(size_t)j * I_DIM];                             \
    } while (0)

#define STORE1(buf, aR, bR)                                            \
    do {                                                               \
        f16x8 p0, p1;                                                  \
        _Pragma("unroll") for (int j = 0; j < 4; ++j) {                \
            p0[j]     = (_Float16)aR[0][j];                            \
            p0[j + 4] = (_Float16)aR[1][j];                            \
            p1[j]     = (_Float16)aR[2][j];                            \
            p1[j + 4] = (_Float16)aR[3][j];                            \
        }                                                              \
        *(f16x8*)&As[buf][ar][((ac2) ^ (ar & 7)) * 8] = p0;            \
        *(f16x8*)&As[buf][ar][((ac2 + 1) ^ (ar & 7)) * 8] = p1;        \
        f16x8 q;                                                       \
        _Pragma("unroll") for (int j = 0; j < 8; ++j)                  \
            q[j] = (_Float16)bR[j];                                    \
        *(f16x8*)&Bs[buf][bn][(bc ^ (bn & 7)) * 8] = q;                \
    } while (0)

    const int KT = 1024 / BK;    // 16, even
    LOAD1(aR0, bR0, 0);
    STORE1(0, aR0, bR0);
    LOAD1(aR0, bR0, BK);
    BAR();
    for (int kt = 0; kt < KT; kt += 2) {
        if (kt + 2 < KT) LOAD1(aR1, bR1, (kt + 2) * BK);
        G_COMPUTE(0);
        if (kt + 1 < KT) STORE1(1, aR0, bR0);
        BAR();
        if (kt + 3 < KT) LOAD1(aR0, bR0, (kt + 3) * BK);
        if (kt + 1 < KT) {
            G_COMPUTE(1);
            if (kt + 2 < KT) STORE1(0, aR1, bR1);
            BAR();
        }
    }
#undef LOAD1
#undef STORE1

    const int rows = cnt - m0;
#pragma unroll
    for (int i = 0; i < 2; ++i) {
#pragma unroll
        for (int rg = 0; rg < 4; ++rg) {
            int r = wm + i * 16 + kq * 4 + rg;
            if (r < rows) {
                int slot = base + m0 + r;
                float* hrow = h32 + (size_t)slot * I_DIM + n0;
#pragma unroll
                for (int j = 0; j < 2; ++j)
                    atomicAdd(&hrow[wn + j * 16 + rsel], acc[i][j][rg]);
            }
        }
    }
}

// ---------------- GEMM2: out[tok, h] += silu(h32[slot,:])*w . w2[e, :, h] ----------------
__global__ __launch_bounds__(NTHR, 4) void k_gemm2(
    const float* __restrict__ h32, const float* __restrict__ W2,
    const int* __restrict__ counts, const int* __restrict__ tok_of_slot,
    const float* __restrict__ w_of_slot, float* __restrict__ out) {
    __shared__ _Float16 As[2][BM][BK];
    __shared__ _Float16 Bs[2][BN][BK];

    const int e = blockIdx.z;
    int base, cnt;
    prefix_of(counts, e, base, cnt);
    const int m0 = blockIdx.y * BM;
    if (m0 >= cnt) return;
    const int n0 = blockIdx.x * BN;
    const int tid = threadIdx.x;

    const int ar = tid >> 2;
    const int ac2 = (tid & 3) * 2;
    const int r_eff = min(ar, cnt - m0 - 1);
    const float* arow = h32 + (size_t)(base + m0 + r_eff) * I_DIM + (tid & 3) * 16;
    const float w_a = w_of_slot[base + m0 + r_eff];

    const int bn = tid & 63;
    const int bc = tid >> 6;
    const float* bcol = W2 + (size_t)e * (I_DIM * H_DIM) + (size_t)(bc * 8) * H_DIM + n0 + bn;

    const int wid = tid >> 6, lane = tid & 63;
    const int wm = (wid >> 1) * 32, wn = (wid & 1) * 32;
    const int rsel = lane & 15, kq = lane >> 4;

    f32x4 acc[2][2] = {};

    float4 aR0[4]; float bR0[8];
    float4 aR1[4]; float bR1[8];

#define LOAD2(aR, bR, k0)                                              \
    do {                                                               \
        aR[0] = *(const float4*)(arow + (k0));                         \
        aR[1] = *(const float4*)(arow + (k0) + 4);                     \
        aR[2] = *(const float4*)(arow + (k0) + 8);                     \
        aR[3] = *(const float4*)(arow + (k0) + 12);                    \
        const float* bp = bcol + (size_t)(k0) * H_DIM;                 \
        _Pragma("unroll") for (int j = 0; j < 8; ++j)                  \
            bR[j] = bp[(size_t)j * H_DIM];                             \
    } while (0)

// A gets silu(v)*w_a at store time (h32 holds raw pre-activation)
#define STORE2(buf, aR, bR)                                            \
    do {                                                               \
        f16x8 p0, p1;                                                  \
        _Pragma("unroll") for (int j = 0; j < 4; ++j) {                \
            float v00 = aR[0][j], v01 = aR[1][j];                      \
            float v10 = aR[2][j], v11 = aR[3][j];                      \
            p0[j]     = (_Float16)(v00 / (1.f + expf(-v00)) * w_a);    \
            p0[j + 4] = (_Float16)(v01 / (1.f + expf(-v01)) * w_a);    \
            p1[j]     = (_Float16)(v10 / (1.f + expf(-v10)) * w_a);    \
            p1[j + 4] = (_Float16)(v11 / (1.f + expf(-v11)) * w_a);    \
        }                                                              \
        *(f16x8*)&As[buf][ar][((ac2) ^ (ar & 7)) * 8] = p0;            \
        *(f16x8*)&As[buf][ar][((ac2 + 1) ^ (ar & 7)) * 8] = p1;        \
        f16x8 q;                                                       \
        _Pragma("unroll") for (int j = 0; j < 8; ++j)                  \
            q[j] = (_Float16)bR[j];                                    \
        *(f16x8*)&Bs[buf][bn][(bc ^ (bn & 7)) * 8] = q;                \
    } while (0)

    const int KT = I_DIM / BK;   // 22, even
    LOAD2(aR0, bR0, 0);
    STORE2(0, aR0, bR0);
    LOAD2(aR0, bR0, BK);
    BAR();
    for (int kt = 0; kt < KT; kt += 2) {
        if (kt + 2 < KT) LOAD2(aR1, bR1, (kt + 2) * BK);
        G_COMPUTE(0);
        if (kt + 1 < KT) STORE2(1, aR0, bR0);
        BAR();
        if (kt + 3 < KT) LOAD2(aR0, bR0, (kt + 3) * BK);
        if (kt + 1 < KT) {
            G_COMPUTE(1);
            if (kt + 2 < KT) STORE2(0, aR1, bR1);
            BAR();
        }
    }
#undef LOAD2
#undef STORE2

    const int rows = cnt - m0;
#pragma unroll
    for (int i = 0; i < 2; ++i) {
#pragma unroll
        for (int rg = 0; rg < 4; ++rg) {
            int r = wm + i * 16 + kq * 4 + rg;
            if (r < rows) {
                int slot = base + m0 + r;
                int tok = tok_of_slot[slot];
                float* orow = out + (size_t)tok * H_DIM + n0;
#pragma unroll
                for (int j = 0; j < 2; ++j)
                    atomicAdd(&orow[wn + j * 16 + rsel], acc[i][j][rg]);
            }
        }
    }
}

extern "C" void kernel_launch(void* const* d_in, const int* in_sizes, int n_in,
                              void* d_out, int out_size, void* d_ws, size_t ws_size,
                              hipStream_t stream) {
    const float* X  = (const float*)d_in[0];
    const float* GW = (const float*)d_in[1];
    const float* W1 = (const float*)d_in[2];
    const float* W2 = (const float*)d_in[3];
    float* out = (float*)d_out;
    char* ws = (char*)d_ws;
    if (ws_size < (size_t)WS_NEEDED) return;

    int*   counts      = (int*)(ws + WS_COUNTS);
    int*   cursors     = (int*)(ws + WS_CURSORS);
    int*   topk_e      = (int*)(ws + WS_TOPK_E);
    float* topk_w      = (float*)(ws + WS_TOPK_W);
    int*   tok_of_slot = (int*)(ws + WS_TOK_OF_SLOT);
    float* w_of_slot   = (float*)(ws + WS_W_OF_SLOT);
    float* h32         = (float*)(ws + WS_H32);

    hipMemsetAsync(ws, 0, 768, stream);                           // counts + cursors
    hipMemsetAsync(h32, 0, (size_t)3072 * I_DIM * sizeof(float), stream);
    k_router<<<T_TOK / 4, 256, 0, stream>>>(X, GW, counts, topk_e, topk_w, out);
    k_scatter<<<T_TOK / 256, 256, 0, stream>>>(topk_e, topk_w, counts, cursors,
                                               tok_of_slot, w_of_slot);
    // gemm1: K-split x2 -> blockIdx.y = mblk (0..7) | kh<<3
    k_gemm1<<<dim3(I_DIM / BN, 16, N_EXP), NTHR, 0, stream>>>(
        X, W1, counts, tok_of_slot, h32);
    // gemm2: natural grid (8 m-blocks max per expert)
    k_gemm2<<<dim3(H_DIM / BN, 8, N_EXP), NTHR, 0, stream>>>(
        h32, W2, counts, tok_of_slot, w_of_slot, out);
}